// Round 4
// baseline (1879.759 us; speedup 1.0000x reference)
//
#include <hip/hip_runtime.h>

// GraphSAGE 2-layer inference, MI355X.
// Round 3: split gather (high-occupancy, wave-per-node) from GEMM (LDS-tiled).
// Inputs: x[N,256] f32, edge_src[E] i32, edge_dst[E] i32, edge_val[E] f32 (unused; recomputed),
//         W1[512,256] f32, b1[256] f32, W2[512,128] f32, b2[128] f32.
// Output: [N,128] f32 (row L2-normalized).

#define N_NODES 100000
#define N_EDGES 3200000
#define DF      256          // feature dim (D_IN == D_HID)
#define K2      512          // 2*DF concat dim

// ------------------------- CSR build -------------------------

__global__ void k_hist(const int* __restrict__ src, int* __restrict__ deg, int E){
  int i = blockIdx.x * blockDim.x + threadIdx.x;
  if(i < E) atomicAdd(&deg[src[i]], 1);
}

// per-block exclusive scan over 1024-element chunks (256 thr x 4)
__global__ void k_scan1(const int* __restrict__ deg, int* __restrict__ rowptr,
                        int* __restrict__ partials, int n){
  __shared__ int s[256];
  const int t = threadIdx.x;
  const int base = blockIdx.x * 1024 + t * 4;
  int v[4], run[4];
  #pragma unroll
  for(int j = 0; j < 4; j++) v[j] = (base + j < n) ? deg[base + j] : 0;
  int sum = 0;
  #pragma unroll
  for(int j = 0; j < 4; j++){ run[j] = sum; sum += v[j]; }
  s[t] = sum;
  __syncthreads();
  for(int off = 1; off < 256; off <<= 1){
    int x = (t >= off) ? s[t - off] : 0;
    __syncthreads();
    s[t] += x;
    __syncthreads();
  }
  const int texcl = s[t] - sum;
  #pragma unroll
  for(int j = 0; j < 4; j++) if(base + j < n) rowptr[base + j] = texcl + run[j];
  if(t == 255) partials[blockIdx.x] = s[255];
}

// single-block exclusive scan of block partials (nb <= 128); also sets rowptr[n]=E
__global__ void k_scan2(int* __restrict__ partials, int nb,
                        int* __restrict__ rowptr, int n, int E){
  __shared__ int s[128];
  const int t = threadIdx.x;
  int v = (t < nb) ? partials[t] : 0;
  s[t] = v;
  __syncthreads();
  for(int off = 1; off < 128; off <<= 1){
    int x = (t >= off) ? s[t - off] : 0;
    __syncthreads();
    s[t] += x;
    __syncthreads();
  }
  if(t < nb) partials[t] = s[t] - v;   // exclusive
  if(t == 0) rowptr[n] = E;
}

__global__ void k_scan3(int* __restrict__ rowptr, const int* __restrict__ partials, int n){
  int i = blockIdx.x * blockDim.x + threadIdx.x;
  if(i < n) rowptr[i] += partials[i >> 10];
}

__global__ void k_fill(const int* __restrict__ src, const int* __restrict__ dst,
                       const int* __restrict__ rowptr, int* __restrict__ cursor,
                       int* __restrict__ col, int E){
  int i = blockIdx.x * blockDim.x + threadIdx.x;
  if(i < E){
    int r = src[i];
    int p = atomicAdd(&cursor[r], 1);
    col[rowptr[r] + p] = dst[i];
  }
}

// ------------------------- gather (mean-aggregate) -------------------------
// One wave per node; 64 lanes x float4 = one 256-f row; 8 neighbor rows in flight.
// No LDS -> high occupancy -> the random row fetches become BW-bound, not latency-bound.

__global__ __launch_bounds__(256)
void k_gather(const float4* __restrict__ f4, const int* __restrict__ rowptr,
              const int* __restrict__ colidx, float4* __restrict__ neigh, int Nn){
  const int node = (blockIdx.x * blockDim.x + threadIdx.x) >> 6;
  const int lane = threadIdx.x & 63;
  if(node >= Nn) return;
  const int s0 = rowptr[node];
  const int s1 = rowptr[node + 1];
  const float invd = (s1 > s0) ? (1.0f / (float)(s1 - s0)) : 0.0f;
  float ax = 0.f, ay = 0.f, az = 0.f, aw = 0.f;
  int e = s0;
  for(; e + 8 <= s1; e += 8){
    int c[8];
    #pragma unroll
    for(int j = 0; j < 8; j++) c[j] = colidx[e + j];
    float4 v[8];
    #pragma unroll
    for(int j = 0; j < 8; j++) v[j] = f4[(size_t)c[j] * (DF/4) + lane];
    #pragma unroll
    for(int j = 0; j < 8; j++){ ax += v[j].x; ay += v[j].y; az += v[j].z; aw += v[j].w; }
  }
  for(; e < s1; ++e){
    const float4 v = f4[(size_t)colidx[e] * (DF/4) + lane];
    ax += v.x; ay += v.y; az += v.z; aw += v.w;
  }
  neigh[(size_t)node * (DF/4) + lane] = make_float4(ax*invd, ay*invd, az*invd, aw*invd);
}

// ------------------------- MLP (concat GEMM + bias + L2norm [+ReLU]) -------------------------
// Per block: 32 nodes. Phase A: coalesced load of self+neigh rows into comb[32][512] (LDS).
// Phase B: comb @ W (f32 register tile, 4 nodes x CPT cols per thread).
// Phase C: +bias, row L2-normalize via shfl reduce, optional ReLU, store.

__device__ __forceinline__ float f4get(const float4& v, int j){
  return (j == 0) ? v.x : (j == 1) ? v.y : (j == 2) ? v.z : v.w;
}

template<int DOUT, bool RELU>
__launch_bounds__(256, 2)
__global__ void k_mlp(const float* __restrict__ feat,
                      const float* __restrict__ neigh,
                      const float* __restrict__ Wm,
                      const float* __restrict__ bias,
                      float* __restrict__ outp)
{
  __shared__ __align__(16) float comb[32][K2];   // 64 KiB -> 2 blocks/CU
  const int t     = threadIdx.x;
  const int node0 = blockIdx.x * 32;             // N % 32 == 0, no tail
  const float4* sf4 = (const float4*)feat;
  const float4* nf4 = (const float4*)neigh;

  // ---- Phase A: coalesced stage. i in [0,2048): row=i>>6, col=i&63 (one wave = one row)
  #pragma unroll
  for(int it = 0; it < 8; it++){
    const int i   = t + it * 256;
    const int row = i >> 6;
    const int col = i & 63;
    *(float4*)&comb[row][col * 4]      = sf4[(size_t)(node0 + row) * (DF/4) + col];
    *(float4*)&comb[row][DF + col * 4] = nf4[(size_t)(node0 + row) * (DF/4) + col];
  }
  __syncthreads();

  // ---- Phase B: GEMM. thread (ng, cg): nodes ng*4..+4, cols cg*CPT..+CPT
  constexpr int CPT = DOUT / 32;   // 8 (DOUT=256) or 4 (DOUT=128)
  constexpr int CQ  = CPT / 4;
  const int cg = t & 31;
  const int ng = t >> 5;
  const int nodeb = ng * 4;
  const int col0  = cg * CPT;
  const float4* W4 = (const float4*)Wm;

  float acc[4][CPT];
  #pragma unroll
  for(int ni = 0; ni < 4; ni++)
    #pragma unroll
    for(int cj = 0; cj < CPT; cj++) acc[ni][cj] = 0.0f;

  for(int k = 0; k < K2; k += 4){
    float4 cv[4];
    #pragma unroll
    for(int ni = 0; ni < 4; ni++) cv[ni] = *(const float4*)&comb[nodeb + ni][k];
    float4 wr[4][CQ];
    #pragma unroll
    for(int kk = 0; kk < 4; kk++)
      #pragma unroll
      for(int q = 0; q < CQ; q++)
        wr[kk][q] = W4[(size_t)(k + kk) * (DOUT/4) + cg * CQ + q];
    #pragma unroll
    for(int kk = 0; kk < 4; kk++){
      float cn[4];
      #pragma unroll
      for(int ni = 0; ni < 4; ni++) cn[ni] = f4get(cv[ni], kk);
      #pragma unroll
      for(int ni = 0; ni < 4; ni++){
        #pragma unroll
        for(int q = 0; q < CQ; q++){
          acc[ni][q*4+0] = fmaf(cn[ni], wr[kk][q].x, acc[ni][q*4+0]);
          acc[ni][q*4+1] = fmaf(cn[ni], wr[kk][q].y, acc[ni][q*4+1]);
          acc[ni][q*4+2] = fmaf(cn[ni], wr[kk][q].z, acc[ni][q*4+2]);
          acc[ni][q*4+3] = fmaf(cn[ni], wr[kk][q].w, acc[ni][q*4+3]);
        }
      }
    }
  }

  // ---- Phase C: bias, L2-normalize (32-lane shfl reduce), ReLU, store
  float bv[CPT];
  #pragma unroll
  for(int cj = 0; cj < CPT; cj++) bv[cj] = bias[col0 + cj];

  #pragma unroll
  for(int ni = 0; ni < 4; ni++){
    float ssq = 0.0f;
    #pragma unroll
    for(int cj = 0; cj < CPT; cj++){
      acc[ni][cj] += bv[cj];
      ssq = fmaf(acc[ni][cj], acc[ni][cj], ssq);
    }
    ssq += __shfl_xor(ssq, 1);
    ssq += __shfl_xor(ssq, 2);
    ssq += __shfl_xor(ssq, 4);
    ssq += __shfl_xor(ssq, 8);
    ssq += __shfl_xor(ssq, 16);
    const float rn = 1.0f / fmaxf(sqrtf(ssq), 1e-12f);
    const int node = node0 + nodeb + ni;
    float4* o4 = (float4*)(outp + (size_t)node * DOUT);
    #pragma unroll
    for(int q = 0; q < CQ; q++){
      float4 v;
      v.x = acc[ni][q*4+0] * rn;
      v.y = acc[ni][q*4+1] * rn;
      v.z = acc[ni][q*4+2] * rn;
      v.w = acc[ni][q*4+3] * rn;
      if(RELU){
        v.x = fmaxf(v.x, 0.0f); v.y = fmaxf(v.y, 0.0f);
        v.z = fmaxf(v.z, 0.0f); v.w = fmaxf(v.w, 0.0f);
      }
      o4[cg * CQ + q] = v;
    }
  }
}

// ------------------------- fallback fused layer (round-2, known-good) -------------------------
// Used only if ws_size can't fit the neigh buffer.

template<int DOUT, bool RELU>
__launch_bounds__(256, 2)
__global__ void k_sage(const float* __restrict__ feat,
                       const float* __restrict__ Wm,
                       const float* __restrict__ bias,
                       const int*  __restrict__ rowptr,
                       const int*  __restrict__ colidx,
                       float* __restrict__ outp)
{
  __shared__ __align__(16) float comb[32][K2];
  const int t     = threadIdx.x;
  const int node0 = blockIdx.x * 32;
  const int wave  = t >> 6;
  const int lane  = t & 63;
  const float4* f4 = (const float4*)feat;

  for(int n = wave; n < 32; n += 4){
    const int node = node0 + n;
    const float4 sf = f4[(size_t)node * (DF/4) + lane];
    const int s0 = rowptr[node];
    const int s1 = rowptr[node + 1];
    const float invd = (s1 > s0) ? (1.0f / (float)(s1 - s0)) : 0.0f;
    float ax = 0.f, ay = 0.f, az = 0.f, aw = 0.f;
    int e = s0;
    for(; e + 4 <= s1; e += 4){
      const int c0 = colidx[e+0], c1 = colidx[e+1], c2 = colidx[e+2], c3 = colidx[e+3];
      const float4 va = f4[(size_t)c0 * (DF/4) + lane];
      const float4 vb = f4[(size_t)c1 * (DF/4) + lane];
      const float4 vc = f4[(size_t)c2 * (DF/4) + lane];
      const float4 vd = f4[(size_t)c3 * (DF/4) + lane];
      ax += va.x + vb.x + vc.x + vd.x;
      ay += va.y + vb.y + vc.y + vd.y;
      az += va.z + vb.z + vc.z + vd.z;
      aw += va.w + vb.w + vc.w + vd.w;
    }
    for(; e < s1; ++e){
      const float4 va = f4[(size_t)colidx[e] * (DF/4) + lane];
      ax += va.x; ay += va.y; az += va.z; aw += va.w;
    }
    float4 nb;
    nb.x = ax * invd; nb.y = ay * invd; nb.z = az * invd; nb.w = aw * invd;
    *(float4*)&comb[n][lane * 4]      = sf;
    *(float4*)&comb[n][DF + lane * 4] = nb;
  }
  __syncthreads();

  constexpr int CPT = DOUT / 32;
  constexpr int CQ  = CPT / 4;
  const int cg = t & 31;
  const int ng = t >> 5;
  const int nodeb = ng * 4;
  const int col0  = cg * CPT;
  const float4* W4 = (const float4*)Wm;

  float acc[4][CPT];
  #pragma unroll
  for(int ni = 0; ni < 4; ni++)
    #pragma unroll
    for(int cj = 0; cj < CPT; cj++) acc[ni][cj] = 0.0f;

  for(int k = 0; k < K2; k += 4){
    float4 cv[4];
    #pragma unroll
    for(int ni = 0; ni < 4; ni++) cv[ni] = *(const float4*)&comb[nodeb + ni][k];
    float4 wr[4][CQ];
    #pragma unroll
    for(int kk = 0; kk < 4; kk++)
      #pragma unroll
      for(int q = 0; q < CQ; q++)
        wr[kk][q] = W4[(size_t)(k + kk) * (DOUT/4) + cg * CQ + q];
    #pragma unroll
    for(int kk = 0; kk < 4; kk++){
      float cn[4];
      #pragma unroll
      for(int ni = 0; ni < 4; ni++) cn[ni] = f4get(cv[ni], kk);
      #pragma unroll
      for(int ni = 0; ni < 4; ni++){
        #pragma unroll
        for(int q = 0; q < CQ; q++){
          acc[ni][q*4+0] = fmaf(cn[ni], wr[kk][q].x, acc[ni][q*4+0]);
          acc[ni][q*4+1] = fmaf(cn[ni], wr[kk][q].y, acc[ni][q*4+1]);
          acc[ni][q*4+2] = fmaf(cn[ni], wr[kk][q].z, acc[ni][q*4+2]);
          acc[ni][q*4+3] = fmaf(cn[ni], wr[kk][q].w, acc[ni][q*4+3]);
        }
      }
    }
  }

  float bv[CPT];
  #pragma unroll
  for(int cj = 0; cj < CPT; cj++) bv[cj] = bias[col0 + cj];

  #pragma unroll
  for(int ni = 0; ni < 4; ni++){
    float ssq = 0.0f;
    #pragma unroll
    for(int cj = 0; cj < CPT; cj++){
      acc[ni][cj] += bv[cj];
      ssq = fmaf(acc[ni][cj], acc[ni][cj], ssq);
    }
    ssq += __shfl_xor(ssq, 1);
    ssq += __shfl_xor(ssq, 2);
    ssq += __shfl_xor(ssq, 4);
    ssq += __shfl_xor(ssq, 8);
    ssq += __shfl_xor(ssq, 16);
    const float rn = 1.0f / fmaxf(sqrtf(ssq), 1e-12f);
    const int node = node0 + nodeb + ni;
    float4* o4 = (float4*)(outp + (size_t)node * DOUT);
    #pragma unroll
    for(int q = 0; q < CQ; q++){
      float4 v;
      v.x = acc[ni][q*4+0] * rn;
      v.y = acc[ni][q*4+1] * rn;
      v.z = acc[ni][q*4+2] * rn;
      v.w = acc[ni][q*4+3] * rn;
      if(RELU){
        v.x = fmaxf(v.x, 0.0f); v.y = fmaxf(v.y, 0.0f);
        v.z = fmaxf(v.z, 0.0f); v.w = fmaxf(v.w, 0.0f);
      }
      o4[cg * CQ + q] = v;
    }
  }
}

// ------------------------- host launch -------------------------

extern "C" void kernel_launch(void* const* d_in, const int* in_sizes, int n_in,
                              void* d_out, int out_size, void* d_ws, size_t ws_size,
                              hipStream_t stream) {
  const float* x    = (const float*)d_in[0];
  const int*   esrc = (const int*)  d_in[1];
  const int*   edst = (const int*)  d_in[2];
  // d_in[3] edge_val: unused — it is exactly 1/deg(src), recomputed from CSR
  const float* W1   = (const float*)d_in[4];
  const float* b1   = (const float*)d_in[5];
  const float* W2   = (const float*)d_in[6];
  const float* b2   = (const float*)d_in[7];
  float* out = (float*)d_out;

  const int N = N_NODES, E = N_EDGES;

  char* ws = (char*)d_ws;
  size_t off = 0;
  auto alloc = [&](size_t bytes) -> void* {
    void* p = ws + off;
    off += (bytes + 255) & ~(size_t)255;
    return p;
  };
  int*   deg      = (int*)  alloc((size_t)N * 4);
  int*   rowptr   = (int*)  alloc((size_t)(N + 1) * 4);
  int*   cursor   = (int*)  alloc((size_t)N * 4);
  int*   partials = (int*)  alloc(512);
  int*   colidx   = (int*)  alloc((size_t)E * 4);
  float* h        = (float*)alloc((size_t)N * DF * 4);
  const size_t base_off = off;
  float* neigh    = (float*)alloc((size_t)N * DF * 4);   // reused by both layers
  const bool split_ok = (off <= ws_size);
  if(base_off > ws_size) return;   // cannot run at all

  const int NBLK_SCAN = (N + 1023) / 1024;   // 98

  hipMemsetAsync(deg,    0, (size_t)N * 4, stream);
  hipMemsetAsync(cursor, 0, (size_t)N * 4, stream);

  k_hist <<<(E + 255) / 256, 256, 0, stream>>>(esrc, deg, E);
  k_scan1<<<NBLK_SCAN,       256, 0, stream>>>(deg, rowptr, partials, N);
  k_scan2<<<1,               128, 0, stream>>>(partials, NBLK_SCAN, rowptr, N, E);
  k_scan3<<<(N + 255) / 256, 256, 0, stream>>>(rowptr, partials, N);
  k_fill <<<(E + 255) / 256, 256, 0, stream>>>(esrc, edst, rowptr, cursor, colidx, E);

  if(split_ok){
    // layer 1
    k_gather<<<N / 4, 256, 0, stream>>>((const float4*)x, rowptr, colidx,
                                        (float4*)neigh, N);
    k_mlp<256, true ><<<N / 32, 256, 0, stream>>>(x, neigh, W1, b1, h);
    // layer 2
    k_gather<<<N / 4, 256, 0, stream>>>((const float4*)h, rowptr, colidx,
                                        (float4*)neigh, N);
    k_mlp<128, false><<<N / 32, 256, 0, stream>>>(h, neigh, W2, b2, out);
  } else {
    k_sage<256, true ><<<N / 32, 256, 0, stream>>>(x, W1, b1, rowptr, colidx, h);
    k_sage<128, false><<<N / 32, 256, 0, stream>>>(h, W2, b2, rowptr, colidx, out);
  }
}

// Round 6
// 890.656 us; speedup vs baseline: 2.1105x; 2.1105x over previous
//
#include <hip/hip_runtime.h>

// GraphSAGE 2-layer inference, MI355X — round 6.
// = round 5 (bf16 gather + MFMA MLP) with graph-replay hardening:
//   - hipMemsetAsync replaced by k_zero kernel (memset graph-node dependency suspect)
//   - colidx reads clamped in gather (no wild loads even under transient corruption)
//   - gather now fetches 2 neighbor rows per wave-instruction (16B/lane uint4)
// Inputs: x[N,256] f32, edge_src[E] i32, edge_dst[E] i32, edge_val[E] f32 (unused; recomputed),
//         W1[512,256] f32, b1[256] f32, W2[512,128] f32, b2[128] f32.
// Output: [N,128] f32 (row L2-normalized).

#define N_NODES 100000
#define N_EDGES 3200000
#define DF      256          // feature dim (D_IN == D_HID)
#define K2      512          // 2*DF concat dim
#define NSK     16           // K2/32 k-steps per MFMA row

typedef __bf16 bf16x8 __attribute__((ext_vector_type(8)));
typedef float  f32x4  __attribute__((ext_vector_type(4)));

__device__ __forceinline__ ushort f2bf(float f){   // RTNE f32 -> bf16
  uint u = __float_as_uint(f);
  u += 0x7fffu + ((u >> 16) & 1u);
  return (ushort)(u >> 16);
}
__device__ __forceinline__ float bflo(uint u){ return __uint_as_float(u << 16); }
__device__ __forceinline__ float bfhi(uint u){ return __uint_as_float(u & 0xffff0000u); }

// ------------------------- zero-init (replaces memset nodes) -------------------------

__global__ void k_zero(int* __restrict__ a, int* __restrict__ b, int n){
  int i = blockIdx.x * blockDim.x + threadIdx.x;
  if(i < n){ a[i] = 0; b[i] = 0; }
}

// ------------------------- CSR build -------------------------

__global__ void k_hist(const int* __restrict__ src, int* __restrict__ deg, int E){
  int i = blockIdx.x * blockDim.x + threadIdx.x;
  if(i < E) atomicAdd(&deg[src[i]], 1);
}

__global__ void k_scan1(const int* __restrict__ deg, int* __restrict__ rowptr,
                        int* __restrict__ partials, int n){
  __shared__ int s[256];
  const int t = threadIdx.x;
  const int base = blockIdx.x * 1024 + t * 4;
  int v[4], run[4];
  #pragma unroll
  for(int j = 0; j < 4; j++) v[j] = (base + j < n) ? deg[base + j] : 0;
  int sum = 0;
  #pragma unroll
  for(int j = 0; j < 4; j++){ run[j] = sum; sum += v[j]; }
  s[t] = sum;
  __syncthreads();
  for(int off = 1; off < 256; off <<= 1){
    int x = (t >= off) ? s[t - off] : 0;
    __syncthreads();
    s[t] += x;
    __syncthreads();
  }
  const int texcl = s[t] - sum;
  #pragma unroll
  for(int j = 0; j < 4; j++) if(base + j < n) rowptr[base + j] = texcl + run[j];
  if(t == 255) partials[blockIdx.x] = s[255];
}

__global__ void k_scan2(int* __restrict__ partials, int nb,
                        int* __restrict__ rowptr, int n, int E){
  __shared__ int s[128];
  const int t = threadIdx.x;
  int v = (t < nb) ? partials[t] : 0;
  s[t] = v;
  __syncthreads();
  for(int off = 1; off < 128; off <<= 1){
    int x = (t >= off) ? s[t - off] : 0;
    __syncthreads();
    s[t] += x;
    __syncthreads();
  }
  if(t < nb) partials[t] = s[t] - v;
  if(t == 0) rowptr[n] = E;
}

__global__ void k_scan3(int* __restrict__ rowptr, const int* __restrict__ partials, int n){
  int i = blockIdx.x * blockDim.x + threadIdx.x;
  if(i < n) rowptr[i] += partials[i >> 10];
}

__global__ void k_fill(const int* __restrict__ src, const int* __restrict__ dst,
                       const int* __restrict__ rowptr, int* __restrict__ cursor,
                       int* __restrict__ col, int E){
  int i = blockIdx.x * blockDim.x + threadIdx.x;
  if(i < E){
    int r = src[i];
    int p = atomicAdd(&cursor[r], 1);
    col[rowptr[r] + p] = dst[i];
  }
}

// ------------------------- f32 -> bf16 mirror -------------------------

__global__ void k_cvt(const float4* __restrict__ x4, uint4* __restrict__ outb, int n8){
  int i = blockIdx.x * blockDim.x + threadIdx.x;
  if(i >= n8) return;
  const float4 p = x4[2*i], q = x4[2*i+1];
  uint4 o;
  o.x = (uint)f2bf(p.x) | ((uint)f2bf(p.y) << 16);
  o.y = (uint)f2bf(p.z) | ((uint)f2bf(p.w) << 16);
  o.z = (uint)f2bf(q.x) | ((uint)f2bf(q.y) << 16);
  o.w = (uint)f2bf(q.z) | ((uint)f2bf(q.w) << 16);
  outb[i] = o;
}

// ------------------------- W fragment pack -------------------------
// B-fragment for mfma_f32_16x16x32_bf16: lane l holds B[k0+(l>>4)*8+i][col0+(l&15)], i=0..7.

template<int DOUT>
__global__ void k_packw(const float* __restrict__ W, uint4* __restrict__ Wp){
  constexpr int NT = DOUT / 16;
  const int tid = blockIdx.x * blockDim.x + threadIdx.x;
  if(tid >= NT * NSK * 64) return;
  const int l   = tid & 63;
  const int s   = (tid >> 6) % NSK;
  const int n   = tid / (64 * NSK);
  const int grp = l >> 4, li = l & 15;
  const int col = n * 16 + li;
  ushort b[8];
  #pragma unroll
  for(int i = 0; i < 8; i++){
    const int k = s * 32 + grp * 8 + i;
    b[i] = f2bf(W[(size_t)k * DOUT + col]);
  }
  uint4 o;
  o.x = (uint)b[0] | ((uint)b[1] << 16);
  o.y = (uint)b[2] | ((uint)b[3] << 16);
  o.z = (uint)b[4] | ((uint)b[5] << 16);
  o.w = (uint)b[6] | ((uint)b[7] << 16);
  Wp[tid] = o;
}

// ------------------------- gather (mean-aggregate, bf16 rows) -------------------------
// One wave per node. Half-wave per edge: lanes 0-31 fetch row c[2j], lanes 32-63 row
// c[2j+1]; each lane loads 16B (8 bf16) -> one instruction fetches TWO 512B rows.
// Halves combined at the end with one shfl_xor(32) pass. Loop counts are node-uniform.

__global__ __launch_bounds__(256)
void k_gather_b(const ushort* __restrict__ xb, const int* __restrict__ rowptr,
                const int* __restrict__ colidx, ushort* __restrict__ nbuf, int Nn){
  const int node = (blockIdx.x * blockDim.x + threadIdx.x) >> 6;
  const int lane = threadIdx.x & 63;
  if(node >= Nn) return;
  const int half = lane >> 5;        // which edge of the pair
  const int li   = lane & 31;        // 16B slice of the 512B row
  const int s0 = rowptr[node];
  const int s1 = rowptr[node + 1];
  const float invd = (s1 > s0) ? (1.0f / (float)(s1 - s0)) : 0.0f;
  const uint cmax = (uint)(Nn - 1);
  float a[8] = {0.f,0.f,0.f,0.f,0.f,0.f,0.f,0.f};
  int e = s0;
  for(; e + 8 <= s1; e += 8){        // 4 pairs: 4 uint4 loads in flight per lane
    uint c[4];
    #pragma unroll
    for(int j = 0; j < 4; j++) c[j] = min((uint)colidx[e + 2*j + half], cmax);
    uint4 v[4];
    #pragma unroll
    for(int j = 0; j < 4; j++) v[j] = *(const uint4*)(xb + (size_t)c[j] * DF + li * 8);
    #pragma unroll
    for(int j = 0; j < 4; j++){
      a[0] += bflo(v[j].x); a[1] += bfhi(v[j].x);
      a[2] += bflo(v[j].y); a[3] += bfhi(v[j].y);
      a[4] += bflo(v[j].z); a[5] += bfhi(v[j].z);
      a[6] += bflo(v[j].w); a[7] += bfhi(v[j].w);
    }
  }
  for(; e + 2 <= s1; e += 2){
    const uint c = min((uint)colidx[e + half], cmax);
    const uint4 v = *(const uint4*)(xb + (size_t)c * DF + li * 8);
    a[0] += bflo(v.x); a[1] += bfhi(v.x);
    a[2] += bflo(v.y); a[3] += bfhi(v.y);
    a[4] += bflo(v.z); a[5] += bfhi(v.z);
    a[6] += bflo(v.w); a[7] += bfhi(v.w);
  }
  if(e < s1 && half == 0){           // odd-degree tail: lanes 0-31 only
    const uint c = min((uint)colidx[e], cmax);
    const uint4 v = *(const uint4*)(xb + (size_t)c * DF + li * 8);
    a[0] += bflo(v.x); a[1] += bfhi(v.x);
    a[2] += bflo(v.y); a[3] += bfhi(v.y);
    a[4] += bflo(v.z); a[5] += bfhi(v.z);
    a[6] += bflo(v.w); a[7] += bfhi(v.w);
  }
  // combine the two half-wave partials
  #pragma unroll
  for(int i = 0; i < 8; i++) a[i] += __shfl_xor(a[i], 32);
  if(half == 0){
    uint4 o;
    o.x = (uint)f2bf(a[0]*invd) | ((uint)f2bf(a[1]*invd) << 16);
    o.y = (uint)f2bf(a[2]*invd) | ((uint)f2bf(a[3]*invd) << 16);
    o.z = (uint)f2bf(a[4]*invd) | ((uint)f2bf(a[5]*invd) << 16);
    o.w = (uint)f2bf(a[6]*invd) | ((uint)f2bf(a[7]*invd) << 16);
    *(uint4*)(nbuf + (size_t)node * DF + li * 8) = o;
  }
}

// ------------------------- MFMA MLP -------------------------
// Per wave: 16 nodes. A (16 x 512 bf16) in 64 VGPRs from xb(k<256)/nb(k>=256):
//   A-frag lane l holds A[l&15][s*32+(l>>4)*8 + i].  B streamed from Wp (L2-hot).
// C layout: col=lane&15, row=(lane>>4)*4+reg -> row L2-norm = shfl_xor {1,2,4,8}.

template<int DOUT, bool RELU, bool OUTBF16>
__launch_bounds__(256, 2)
__global__ void k_mlp_mfma(const ushort* __restrict__ xb, const ushort* __restrict__ nb,
                           const uint4* __restrict__ Wp, const float* __restrict__ bias,
                           ushort* __restrict__ outb, float* __restrict__ outf, int Nn)
{
  constexpr int NT = DOUT / 16;
  const int l     = threadIdx.x & 63;
  const int w     = threadIdx.x >> 6;
  const int nodeb = blockIdx.x * 64 + w * 16;
  const int grp   = l >> 4;
  const int li    = l & 15;

  const int rowL = min(nodeb + li, Nn - 1);
  const ushort* xr = xb + (size_t)rowL * DF;
  const ushort* nr = nb + (size_t)rowL * DF;
  uint4 a[NSK];
  #pragma unroll
  for(int s = 0; s < 8; s++) a[s]     = *(const uint4*)(xr + s * 32 + grp * 8);
  #pragma unroll
  for(int s = 0; s < 8; s++) a[s + 8] = *(const uint4*)(nr + s * 32 + grp * 8);

  f32x4 acc[NT];
  #pragma unroll
  for(int n = 0; n < NT; n++){
    f32x4 c = {0.f, 0.f, 0.f, 0.f};
    #pragma unroll
    for(int s = 0; s < NSK; s++){
      const uint4 b = Wp[(size_t)(n * NSK + s) * 64 + l];
      c = __builtin_amdgcn_mfma_f32_16x16x32_bf16(
            __builtin_bit_cast(bf16x8, a[s]),
            __builtin_bit_cast(bf16x8, b), c, 0, 0, 0);
    }
    acc[n] = c;
  }

  #pragma unroll
  for(int n = 0; n < NT; n++){
    const float bv = bias[n * 16 + li];
    acc[n][0] += bv; acc[n][1] += bv; acc[n][2] += bv; acc[n][3] += bv;
  }

  float rn[4];
  #pragma unroll
  for(int r = 0; r < 4; r++){
    float ss = 0.f;
    #pragma unroll
    for(int n = 0; n < NT; n++) ss = fmaf(acc[n][r], acc[n][r], ss);
    ss += __shfl_xor(ss, 1);
    ss += __shfl_xor(ss, 2);
    ss += __shfl_xor(ss, 4);
    ss += __shfl_xor(ss, 8);
    rn[r] = 1.0f / fmaxf(sqrtf(ss), 1e-12f);
  }

  #pragma unroll
  for(int r = 0; r < 4; r++){
    const int node = nodeb + grp * 4 + r;
    if(node < Nn){
      #pragma unroll
      for(int n = 0; n < NT; n++){
        float y = acc[n][r] * rn[r];
        if(RELU) y = fmaxf(y, 0.0f);
        const size_t idx = (size_t)node * DOUT + n * 16 + li;
        if(OUTBF16) outb[idx] = f2bf(y);
        else        outf[idx] = y;
      }
    }
  }
}

// ------------------------- host launch -------------------------

extern "C" void kernel_launch(void* const* d_in, const int* in_sizes, int n_in,
                              void* d_out, int out_size, void* d_ws, size_t ws_size,
                              hipStream_t stream) {
  const float* x    = (const float*)d_in[0];
  const int*   esrc = (const int*)  d_in[1];
  const int*   edst = (const int*)  d_in[2];
  // d_in[3] edge_val unused — it equals 1/deg(src), recomputed from CSR
  const float* W1   = (const float*)d_in[4];
  const float* b1   = (const float*)d_in[5];
  const float* W2   = (const float*)d_in[6];
  const float* b2   = (const float*)d_in[7];
  float* out = (float*)d_out;

  const int N = N_NODES, E = N_EDGES;

  char* ws = (char*)d_ws;
  size_t off = 0;
  auto alloc = [&](size_t bytes) -> void* {
    void* p = ws + off;
    off += (bytes + 255) & ~(size_t)255;
    return p;
  };
  int*    deg      = (int*)   alloc((size_t)N * 4);
  int*    rowptr   = (int*)   alloc((size_t)(N + 1) * 4);
  int*    cursor   = (int*)   alloc((size_t)N * 4);
  int*    partials = (int*)   alloc(512);
  int*    colidx   = (int*)   alloc((size_t)E * 4);
  ushort* xbuf     = (ushort*)alloc((size_t)N * DF * 2);
  ushort* hbuf     = (ushort*)alloc((size_t)N * DF * 2);
  ushort* nbuf     = (ushort*)alloc((size_t)N * DF * 2);
  uint4*  Wp1      = (uint4*) alloc((size_t)16 * NSK * 64 * 16);
  uint4*  Wp2      = (uint4*) alloc((size_t) 8 * NSK * 64 * 16);
  if(off > ws_size) return;

  const int NBLK_SCAN = (N + 1023) / 1024;   // 98

  k_zero <<<(N + 255) / 256, 256, 0, stream>>>(deg, cursor, N);
  k_hist <<<(E + 255) / 256, 256, 0, stream>>>(esrc, deg, E);
  k_scan1<<<NBLK_SCAN,       256, 0, stream>>>(deg, rowptr, partials, N);
  k_scan2<<<1,               128, 0, stream>>>(partials, NBLK_SCAN, rowptr, N, E);
  k_scan3<<<(N + 255) / 256, 256, 0, stream>>>(rowptr, partials, N);
  k_fill <<<(E + 255) / 256, 256, 0, stream>>>(esrc, edst, rowptr, cursor, colidx, E);

  const int n8 = N * DF / 8;
  k_cvt<<<(n8 + 255) / 256, 256, 0, stream>>>((const float4*)x, (uint4*)xbuf, n8);
  k_packw<256><<<(16 * NSK * 64 + 255) / 256, 256, 0, stream>>>(W1, Wp1);
  k_packw<128><<<( 8 * NSK * 64 + 255) / 256, 256, 0, stream>>>(W2, Wp2);

  const int GRID_MLP = (N + 63) / 64;

  k_gather_b<<<N / 4, 256, 0, stream>>>(xbuf, rowptr, colidx, nbuf, N);
  k_mlp_mfma<256, true,  true ><<<GRID_MLP, 256, 0, stream>>>(xbuf, nbuf, Wp1, b1,
                                                              hbuf, nullptr, N);
  k_gather_b<<<N / 4, 256, 0, stream>>>(hbuf, rowptr, colidx, nbuf, N);
  k_mlp_mfma<128, false, false><<<GRID_MLP, 256, 0, stream>>>(hbuf, nbuf, Wp2, b2,
                                                              nullptr, out, N);
}

// Round 7
// 773.898 us; speedup vs baseline: 2.4289x; 1.1509x over previous
//
#include <hip/hip_runtime.h>

// GraphSAGE 2-layer inference, MI355X — round 7.
// = round 6 (bf16 gather + MFMA MLP, graph-safe zero kernels) plus:
//   - layer 2 restructured as project-then-aggregate:
//       P = h @ W2_bot   (N x 128, bf16)   -> gather reads 256B rows (half traffic)
//       out = normalize(h @ W2_top + mean_gather(P) + b2)
//   - gather kernel templated over feature dim (512B or 256B rows)
//   - k_zero folded into k_cvt (one fewer dispatch)
// Inputs: x[N,256] f32, edge_src[E] i32, edge_dst[E] i32, edge_val[E] f32 (unused; recomputed),
//         W1[512,256] f32, b1[256] f32, W2[512,128] f32, b2[128] f32.
// Output: [N,128] f32 (row L2-normalized).

#define N_NODES 100000
#define N_EDGES 3200000
#define DF      256          // feature dim (D_IN == D_HID)

typedef __bf16 bf16x8 __attribute__((ext_vector_type(8)));
typedef float  f32x4  __attribute__((ext_vector_type(4)));

__device__ __forceinline__ ushort f2bf(float f){   // RTNE f32 -> bf16
  uint u = __float_as_uint(f);
  u += 0x7fffu + ((u >> 16) & 1u);
  return (ushort)(u >> 16);
}
__device__ __forceinline__ float bflo(uint u){ return __uint_as_float(u << 16); }
__device__ __forceinline__ float bfhi(uint u){ return __uint_as_float(u & 0xffff0000u); }
__device__ __forceinline__ float bfs(ushort u){ return __uint_as_float((uint)u << 16); }

// ------------------------- CSR build -------------------------

__global__ void k_hist(const int* __restrict__ src, int* __restrict__ deg, int E){
  int i = blockIdx.x * blockDim.x + threadIdx.x;
  if(i < E) atomicAdd(&deg[src[i]], 1);
}

__global__ void k_scan1(const int* __restrict__ deg, int* __restrict__ rowptr,
                        int* __restrict__ partials, int n){
  __shared__ int s[256];
  const int t = threadIdx.x;
  const int base = blockIdx.x * 1024 + t * 4;
  int v[4], run[4];
  #pragma unroll
  for(int j = 0; j < 4; j++) v[j] = (base + j < n) ? deg[base + j] : 0;
  int sum = 0;
  #pragma unroll
  for(int j = 0; j < 4; j++){ run[j] = sum; sum += v[j]; }
  s[t] = sum;
  __syncthreads();
  for(int off = 1; off < 256; off <<= 1){
    int x = (t >= off) ? s[t - off] : 0;
    __syncthreads();
    s[t] += x;
    __syncthreads();
  }
  const int texcl = s[t] - sum;
  #pragma unroll
  for(int j = 0; j < 4; j++) if(base + j < n) rowptr[base + j] = texcl + run[j];
  if(t == 255) partials[blockIdx.x] = s[255];
}

__global__ void k_scan2(int* __restrict__ partials, int nb,
                        int* __restrict__ rowptr, int n, int E){
  __shared__ int s[128];
  const int t = threadIdx.x;
  int v = (t < nb) ? partials[t] : 0;
  s[t] = v;
  __syncthreads();
  for(int off = 1; off < 128; off <<= 1){
    int x = (t >= off) ? s[t - off] : 0;
    __syncthreads();
    s[t] += x;
    __syncthreads();
  }
  if(t < nb) partials[t] = s[t] - v;
  if(t == 0) rowptr[n] = E;
}

__global__ void k_scan3(int* __restrict__ rowptr, const int* __restrict__ partials, int n){
  int i = blockIdx.x * blockDim.x + threadIdx.x;
  if(i < n) rowptr[i] += partials[i >> 10];
}

__global__ void k_fill(const int* __restrict__ src, const int* __restrict__ dst,
                       const int* __restrict__ rowptr, int* __restrict__ cursor,
                       int* __restrict__ col, int E){
  int i = blockIdx.x * blockDim.x + threadIdx.x;
  if(i < E){
    int r = src[i];
    int p = atomicAdd(&cursor[r], 1);
    col[rowptr[r] + p] = dst[i];
  }
}

// ------------------------- f32 -> bf16 mirror (+ zero deg/cursor) -------------------------

__global__ void k_cvt(const float4* __restrict__ x4, uint4* __restrict__ outb, int n8,
                      int* __restrict__ za, int* __restrict__ zb, int nz){
  int i = blockIdx.x * blockDim.x + threadIdx.x;
  if(i < nz){ za[i] = 0; zb[i] = 0; }
  if(i >= n8) return;
  const float4 p = x4[2*i], q = x4[2*i+1];
  uint4 o;
  o.x = (uint)f2bf(p.x) | ((uint)f2bf(p.y) << 16);
  o.y = (uint)f2bf(p.z) | ((uint)f2bf(p.w) << 16);
  o.z = (uint)f2bf(q.x) | ((uint)f2bf(q.y) << 16);
  o.w = (uint)f2bf(q.z) | ((uint)f2bf(q.w) << 16);
  outb[i] = o;
}

// ------------------------- W fragment pack -------------------------
// B-fragment for mfma_f32_16x16x32_bf16: lane l holds B[k0+(l>>4)*8+i][col0+(l&15)], i=0..7.
// Fragment (n-tile, k-step) contiguous: uint4 index ((n*ksteps+s)*64+l). krow0 selects W rows.

template<int DOUT>
__global__ void k_packw(const float* __restrict__ W, uint4* __restrict__ Wp,
                        int ksteps, int krow0){
  constexpr int NT = DOUT / 16;
  const int tid = blockIdx.x * blockDim.x + threadIdx.x;
  if(tid >= NT * ksteps * 64) return;
  const int l   = tid & 63;
  const int s   = (tid >> 6) % ksteps;
  const int n   = tid / (64 * ksteps);
  const int grp = l >> 4, li = l & 15;
  const int col = n * 16 + li;
  ushort b[8];
  #pragma unroll
  for(int i = 0; i < 8; i++){
    const int k = krow0 + s * 32 + grp * 8 + i;
    b[i] = f2bf(W[(size_t)k * DOUT + col]);
  }
  uint4 o;
  o.x = (uint)b[0] | ((uint)b[1] << 16);
  o.y = (uint)b[2] | ((uint)b[3] << 16);
  o.z = (uint)b[4] | ((uint)b[5] << 16);
  o.w = (uint)b[6] | ((uint)b[7] << 16);
  Wp[tid] = o;
}

// ------------------------- gather (mean-aggregate, bf16 rows) -------------------------
// One wave per node, templated on feature dim. LPR = lanes per row (row = DIMV*2 bytes,
// 16B per lane); EPG = 64/LPR edges fetched per instruction. Main loop keeps 4 uint4
// loads in flight. Partials combined with shfl_xor passes; lanes < LPR store.

template<int DIMV>
__global__ __launch_bounds__(256)
void k_gather_b(const ushort* __restrict__ xb, const int* __restrict__ rowptr,
                const int* __restrict__ colidx, ushort* __restrict__ nbuf, int Nn){
  constexpr int LPR = DIMV / 8;      // 32 (dim 256) or 16 (dim 128)
  constexpr int EPG = 64 / LPR;      // 2 or 4 edges per instruction group
  const int node = (blockIdx.x * blockDim.x + threadIdx.x) >> 6;
  const int lane = threadIdx.x & 63;
  if(node >= Nn) return;
  const int half = lane / LPR;       // edge slot within group
  const int li   = lane % LPR;       // 16B slice of the row
  const int s0 = rowptr[node];
  const int s1 = rowptr[node + 1];
  const float invd = (s1 > s0) ? (1.0f / (float)(s1 - s0)) : 0.0f;
  const uint cmax = (uint)(Nn - 1);
  float a[8] = {0.f,0.f,0.f,0.f,0.f,0.f,0.f,0.f};
  int e = s0;
  for(; e + 4 * EPG <= s1; e += 4 * EPG){   // 4 uint4 loads in flight per lane
    uint c[4];
    #pragma unroll
    for(int j = 0; j < 4; j++) c[j] = min((uint)colidx[e + j * EPG + half], cmax);
    uint4 v[4];
    #pragma unroll
    for(int j = 0; j < 4; j++) v[j] = *(const uint4*)(xb + (size_t)c[j] * DIMV + li * 8);
    #pragma unroll
    for(int j = 0; j < 4; j++){
      a[0] += bflo(v[j].x); a[1] += bfhi(v[j].x);
      a[2] += bflo(v[j].y); a[3] += bfhi(v[j].y);
      a[4] += bflo(v[j].z); a[5] += bfhi(v[j].z);
      a[6] += bflo(v[j].w); a[7] += bfhi(v[j].w);
    }
  }
  for(; e + EPG <= s1; e += EPG){
    const uint c = min((uint)colidx[e + half], cmax);
    const uint4 v = *(const uint4*)(xb + (size_t)c * DIMV + li * 8);
    a[0] += bflo(v.x); a[1] += bfhi(v.x);
    a[2] += bflo(v.y); a[3] += bfhi(v.y);
    a[4] += bflo(v.z); a[5] += bfhi(v.z);
    a[6] += bflo(v.w); a[7] += bfhi(v.w);
  }
  if(half < s1 - e){                 // remainder (< EPG edges)
    const uint c = min((uint)colidx[e + half], cmax);
    const uint4 v = *(const uint4*)(xb + (size_t)c * DIMV + li * 8);
    a[0] += bflo(v.x); a[1] += bfhi(v.x);
    a[2] += bflo(v.y); a[3] += bfhi(v.y);
    a[4] += bflo(v.z); a[5] += bfhi(v.z);
    a[6] += bflo(v.w); a[7] += bfhi(v.w);
  }
  #pragma unroll
  for(int off = LPR; off < 64; off <<= 1)
    #pragma unroll
    for(int i = 0; i < 8; i++) a[i] += __shfl_xor(a[i], off);
  if(lane < LPR){
    uint4 o;
    o.x = (uint)f2bf(a[0]*invd) | ((uint)f2bf(a[1]*invd) << 16);
    o.y = (uint)f2bf(a[2]*invd) | ((uint)f2bf(a[3]*invd) << 16);
    o.z = (uint)f2bf(a[4]*invd) | ((uint)f2bf(a[5]*invd) << 16);
    o.w = (uint)f2bf(a[6]*invd) | ((uint)f2bf(a[7]*invd) << 16);
    *(uint4*)(nbuf + (size_t)node * DIMV + li * 8) = o;
  }
}

// ------------------------- MFMA MLP / projection -------------------------
// Per wave: 16 nodes. A (16 x KS*32 bf16) in registers; A-frag lane l holds
// A[l&15][s*32+(l>>4)*8+i]. TWOSRC: first KS/2 k-steps from A0 row, rest from A1 row
// (concat). B streamed from Wp (L2-hot). C layout: col=lane&15, row=(lane>>4)*4+reg.
// ADDG adds a pre-gathered bf16 [Nn,DOUT] term before bias/norm.
// NORM: +bias, row-L2-normalize (shfl_xor over the 16-lane group).

template<int DOUT, int KS, bool TWOSRC, bool ADDG, bool RELU, bool NORM, bool OUTBF16>
__launch_bounds__(256, 2)
__global__ void k_mlp(const ushort* __restrict__ A0, const ushort* __restrict__ A1,
                      const uint4* __restrict__ Wp, const float* __restrict__ bias,
                      const ushort* __restrict__ g,
                      ushort* __restrict__ outb, float* __restrict__ outf, int Nn)
{
  constexpr int NT   = DOUT / 16;
  constexpr int DIMA = TWOSRC ? KS * 16 : KS * 32;   // row length of A0 (and A1)
  const int l     = threadIdx.x & 63;
  const int w     = threadIdx.x >> 6;
  const int nodeb = blockIdx.x * 64 + w * 16;
  const int grp   = l >> 4;
  const int li    = l & 15;

  const int rowL = min(nodeb + li, Nn - 1);
  uint4 a[KS];
  if(TWOSRC){
    const ushort* xr = A0 + (size_t)rowL * DIMA;
    const ushort* nr = A1 + (size_t)rowL * DIMA;
    #pragma unroll
    for(int s = 0; s < KS/2; s++) a[s]        = *(const uint4*)(xr + s * 32 + grp * 8);
    #pragma unroll
    for(int s = 0; s < KS/2; s++) a[s + KS/2] = *(const uint4*)(nr + s * 32 + grp * 8);
  } else {
    const ushort* xr = A0 + (size_t)rowL * DIMA;
    #pragma unroll
    for(int s = 0; s < KS; s++) a[s] = *(const uint4*)(xr + s * 32 + grp * 8);
  }

  f32x4 acc[NT];
  #pragma unroll
  for(int n = 0; n < NT; n++){
    f32x4 c = {0.f, 0.f, 0.f, 0.f};
    #pragma unroll
    for(int s = 0; s < KS; s++){
      const uint4 b = Wp[(size_t)(n * KS + s) * 64 + l];
      c = __builtin_amdgcn_mfma_f32_16x16x32_bf16(
            __builtin_bit_cast(bf16x8, a[s]),
            __builtin_bit_cast(bf16x8, b), c, 0, 0, 0);
    }
    acc[n] = c;
  }

  if(NORM){
    #pragma unroll
    for(int n = 0; n < NT; n++){
      const float bv = bias[n * 16 + li];
      acc[n][0] += bv; acc[n][1] += bv; acc[n][2] += bv; acc[n][3] += bv;
    }
  }

  if(ADDG){
    #pragma unroll
    for(int r = 0; r < 4; r++){
      const int rowg = min(nodeb + grp * 4 + r, Nn - 1);
      #pragma unroll
      for(int n = 0; n < NT; n++)
        acc[n][r] += bfs(g[(size_t)rowg * DOUT + n * 16 + li]);
    }
  }

  float rn[4] = {1.f, 1.f, 1.f, 1.f};
  if(NORM){
    #pragma unroll
    for(int r = 0; r < 4; r++){
      float ss = 0.f;
      #pragma unroll
      for(int n = 0; n < NT; n++) ss = fmaf(acc[n][r], acc[n][r], ss);
      ss += __shfl_xor(ss, 1);
      ss += __shfl_xor(ss, 2);
      ss += __shfl_xor(ss, 4);
      ss += __shfl_xor(ss, 8);
      rn[r] = 1.0f / fmaxf(sqrtf(ss), 1e-12f);
    }
  }

  #pragma unroll
  for(int r = 0; r < 4; r++){
    const int node = nodeb + grp * 4 + r;
    if(node < Nn){
      #pragma unroll
      for(int n = 0; n < NT; n++){
        float y = acc[n][r];
        if(NORM) y *= rn[r];
        if(RELU) y = fmaxf(y, 0.0f);
        const size_t idx = (size_t)node * DOUT + n * 16 + li;
        if(OUTBF16) outb[idx] = f2bf(y);
        else        outf[idx] = y;
      }
    }
  }
}

// ------------------------- host launch -------------------------

extern "C" void kernel_launch(void* const* d_in, const int* in_sizes, int n_in,
                              void* d_out, int out_size, void* d_ws, size_t ws_size,
                              hipStream_t stream) {
  const float* x    = (const float*)d_in[0];
  const int*   esrc = (const int*)  d_in[1];
  const int*   edst = (const int*)  d_in[2];
  // d_in[3] edge_val unused — it equals 1/deg(src), recomputed from CSR
  const float* W1   = (const float*)d_in[4];
  const float* b1   = (const float*)d_in[5];
  const float* W2   = (const float*)d_in[6];
  const float* b2   = (const float*)d_in[7];
  float* out = (float*)d_out;

  const int N = N_NODES, E = N_EDGES;

  char* ws = (char*)d_ws;
  size_t off = 0;
  auto alloc = [&](size_t bytes) -> void* {
    void* p = ws + off;
    off += (bytes + 255) & ~(size_t)255;
    return p;
  };
  int*    deg      = (int*)   alloc((size_t)N * 4);
  int*    rowptr   = (int*)   alloc((size_t)(N + 1) * 4);
  int*    cursor   = (int*)   alloc((size_t)N * 4);
  int*    partials = (int*)   alloc(512);
  int*    colidx   = (int*)   alloc((size_t)E * 4);
  ushort* xbuf     = (ushort*)alloc((size_t)N * DF * 2);   // bf16 mirror of x
  ushort* hbuf     = (ushort*)alloc((size_t)N * DF * 2);   // bf16 h (layer-1 out)
  ushort* nbuf     = (ushort*)alloc((size_t)N * DF * 2);   // layer1 neigh; reused as Pb|gb
  uint4*  Wp1      = (uint4*) alloc((size_t)16 * 16 * 64 * 16);  // W1: NT=16, KS=16
  uint4*  Wp2a     = (uint4*) alloc((size_t) 8 *  8 * 64 * 16);  // W2 rows 0..255
  uint4*  Wp2b     = (uint4*) alloc((size_t) 8 *  8 * 64 * 16);  // W2 rows 256..511
  if(off > ws_size) return;

  ushort* Pb = nbuf;                       // [N,128] bf16 projected features
  ushort* gb = nbuf + (size_t)N * 128;     // [N,128] bf16 gathered projection

  const int NBLK_SCAN = (N + 1023) / 1024;   // 98
  const int n8 = N * DF / 8;

  // bf16 mirror of x + zero deg/cursor in one pass
  k_cvt<<<(n8 + 255) / 256, 256, 0, stream>>>((const float4*)x, (uint4*)xbuf, n8,
                                              deg, cursor, N);
  k_packw<256><<<(16 * 16 * 64 + 255) / 256, 256, 0, stream>>>(W1,  Wp1, 16, 0);
  k_packw<128><<<( 8 *  8 * 64 + 255) / 256, 256, 0, stream>>>(W2, Wp2a,  8, 0);
  k_packw<128><<<( 8 *  8 * 64 + 255) / 256, 256, 0, stream>>>(W2, Wp2b,  8, 256);

  k_hist <<<(E + 255) / 256, 256, 0, stream>>>(esrc, deg, E);
  k_scan1<<<NBLK_SCAN,       256, 0, stream>>>(deg, rowptr, partials, N);
  k_scan2<<<1,               128, 0, stream>>>(partials, NBLK_SCAN, rowptr, N, E);
  k_scan3<<<(N + 255) / 256, 256, 0, stream>>>(rowptr, partials, N);
  k_fill <<<(E + 255) / 256, 256, 0, stream>>>(esrc, edst, rowptr, cursor, colidx, E);

  const int GRID_MLP = (N + 63) / 64;   // 1563, tail-guarded

  // ---- layer 1: h = relu(normalize([x | mean(x)] @ W1 + b1))
  k_gather_b<256><<<N / 4, 256, 0, stream>>>(xbuf, rowptr, colidx, nbuf, N);
  k_mlp<256, 16, true, false, true, true, true>
      <<<GRID_MLP, 256, 0, stream>>>(xbuf, nbuf, Wp1, b1, nullptr, hbuf, nullptr, N);

  // ---- layer 2 (project-then-aggregate):
  //   P = h @ W2_bot ; out = normalize(h @ W2_top + mean(P) + b2)
  k_mlp<128, 8, false, false, false, false, true>
      <<<GRID_MLP, 256, 0, stream>>>(hbuf, nullptr, Wp2b, nullptr, nullptr, Pb, nullptr, N);
  k_gather_b<128><<<N / 4, 256, 0, stream>>>(Pb, rowptr, colidx, gb, N);
  k_mlp<128, 8, false, true, false, true, false>
      <<<GRID_MLP, 256, 0, stream>>>(hbuf, nullptr, Wp2a, b2, gb, nullptr, out, N);
}

// Round 8
// 677.249 us; speedup vs baseline: 2.7756x; 1.1427x over previous
//
#include <hip/hip_runtime.h>

// GraphSAGE 2-layer inference, MI355X — round 8.
// = round 7 plus: layer-1 gather reads an fp8(e4m3) mirror of x (256B rows,
//   25.6MB table) decoded with v_cvt_pk_f32_fp8; self-term stays bf16.
// Inputs: x[N,256] f32, edge_src[E] i32, edge_dst[E] i32, edge_val[E] f32 (unused; recomputed),
//         W1[512,256] f32, b1[256] f32, W2[512,128] f32, b2[128] f32.
// Output: [N,128] f32 (row L2-normalized).

#define N_NODES 100000
#define N_EDGES 3200000
#define DF      256          // feature dim (D_IN == D_HID)

typedef __bf16 bf16x8 __attribute__((ext_vector_type(8)));
typedef float  f32x4  __attribute__((ext_vector_type(4)));
typedef float  f32x2  __attribute__((ext_vector_type(2)));

__device__ __forceinline__ ushort f2bf(float f){   // RTNE f32 -> bf16
  uint u = __float_as_uint(f);
  u += 0x7fffu + ((u >> 16) & 1u);
  return (ushort)(u >> 16);
}
__device__ __forceinline__ float bflo(uint u){ return __uint_as_float(u << 16); }
__device__ __forceinline__ float bfhi(uint u){ return __uint_as_float(u & 0xffff0000u); }
__device__ __forceinline__ float bfs(ushort u){ return __uint_as_float((uint)u << 16); }

// ------------------------- CSR build -------------------------

__global__ void k_hist(const int* __restrict__ src, int* __restrict__ deg, int E){
  int i = blockIdx.x * blockDim.x + threadIdx.x;
  if(i < E) atomicAdd(&deg[src[i]], 1);
}

__global__ void k_scan1(const int* __restrict__ deg, int* __restrict__ rowptr,
                        int* __restrict__ partials, int n){
  __shared__ int s[256];
  const int t = threadIdx.x;
  const int base = blockIdx.x * 1024 + t * 4;
  int v[4], run[4];
  #pragma unroll
  for(int j = 0; j < 4; j++) v[j] = (base + j < n) ? deg[base + j] : 0;
  int sum = 0;
  #pragma unroll
  for(int j = 0; j < 4; j++){ run[j] = sum; sum += v[j]; }
  s[t] = sum;
  __syncthreads();
  for(int off = 1; off < 256; off <<= 1){
    int x = (t >= off) ? s[t - off] : 0;
    __syncthreads();
    s[t] += x;
    __syncthreads();
  }
  const int texcl = s[t] - sum;
  #pragma unroll
  for(int j = 0; j < 4; j++) if(base + j < n) rowptr[base + j] = texcl + run[j];
  if(t == 255) partials[blockIdx.x] = s[255];
}

__global__ void k_scan2(int* __restrict__ partials, int nb,
                        int* __restrict__ rowptr, int n, int E){
  __shared__ int s[128];
  const int t = threadIdx.x;
  int v = (t < nb) ? partials[t] : 0;
  s[t] = v;
  __syncthreads();
  for(int off = 1; off < 128; off <<= 1){
    int x = (t >= off) ? s[t - off] : 0;
    __syncthreads();
    s[t] += x;
    __syncthreads();
  }
  if(t < nb) partials[t] = s[t] - v;
  if(t == 0) rowptr[n] = E;
}

__global__ void k_scan3(int* __restrict__ rowptr, const int* __restrict__ partials, int n){
  int i = blockIdx.x * blockDim.x + threadIdx.x;
  if(i < n) rowptr[i] += partials[i >> 10];
}

__global__ void k_fill(const int* __restrict__ src, const int* __restrict__ dst,
                       const int* __restrict__ rowptr, int* __restrict__ cursor,
                       int* __restrict__ col, int E){
  int i = blockIdx.x * blockDim.x + threadIdx.x;
  if(i < E){
    int r = src[i];
    int p = atomicAdd(&cursor[r], 1);
    col[rowptr[r] + p] = dst[i];
  }
}

// ------------- f32 -> bf16 + fp8(e4m3) mirrors (+ zero deg/cursor) -------------

__global__ void k_cvt(const float4* __restrict__ x4, uint4* __restrict__ outb,
                      uint2* __restrict__ outq, int n8,
                      int* __restrict__ za, int* __restrict__ zb, int nz){
  int i = blockIdx.x * blockDim.x + threadIdx.x;
  if(i < nz){ za[i] = 0; zb[i] = 0; }
  if(i >= n8) return;
  const float4 p = x4[2*i], q = x4[2*i+1];
  uint4 o;
  o.x = (uint)f2bf(p.x) | ((uint)f2bf(p.y) << 16);
  o.y = (uint)f2bf(p.z) | ((uint)f2bf(p.w) << 16);
  o.z = (uint)f2bf(q.x) | ((uint)f2bf(q.y) << 16);
  o.w = (uint)f2bf(q.z) | ((uint)f2bf(q.w) << 16);
  outb[i] = o;
  uint w0 = __builtin_amdgcn_cvt_pk_fp8_f32(p.x, p.y, 0u, false);
  w0      = __builtin_amdgcn_cvt_pk_fp8_f32(p.z, p.w, w0, true);
  uint w1 = __builtin_amdgcn_cvt_pk_fp8_f32(q.x, q.y, 0u, false);
  w1      = __builtin_amdgcn_cvt_pk_fp8_f32(q.z, q.w, w1, true);
  outq[i] = make_uint2(w0, w1);
}

// ------------------------- W fragment pack -------------------------
// B-fragment for mfma_f32_16x16x32_bf16: lane l holds B[k0+(l>>4)*8+i][col0+(l&15)], i=0..7.

template<int DOUT>
__global__ void k_packw(const float* __restrict__ W, uint4* __restrict__ Wp,
                        int ksteps, int krow0){
  constexpr int NT = DOUT / 16;
  const int tid = blockIdx.x * blockDim.x + threadIdx.x;
  if(tid >= NT * ksteps * 64) return;
  const int l   = tid & 63;
  const int s   = (tid >> 6) % ksteps;
  const int n   = tid / (64 * ksteps);
  const int grp = l >> 4, li = l & 15;
  const int col = n * 16 + li;
  ushort b[8];
  #pragma unroll
  for(int i = 0; i < 8; i++){
    const int k = krow0 + s * 32 + grp * 8 + i;
    b[i] = f2bf(W[(size_t)k * DOUT + col]);
  }
  uint4 o;
  o.x = (uint)b[0] | ((uint)b[1] << 16);
  o.y = (uint)b[2] | ((uint)b[3] << 16);
  o.z = (uint)b[4] | ((uint)b[5] << 16);
  o.w = (uint)b[6] | ((uint)b[7] << 16);
  Wp[tid] = o;
}

// ------------------ gather from fp8 table (dim 256, mean -> bf16) ------------------
// One wave per node; 16 lanes per 256B row (16B = 16 fp8 each), 4 edges per group,
// 4 uint4 loads in flight. Decode via v_cvt_pk_f32_fp8. Reduce with shfl_xor(16,32).

__global__ __launch_bounds__(256)
void k_gather_q(const uchar* __restrict__ xq, const int* __restrict__ rowptr,
                const int* __restrict__ colidx, ushort* __restrict__ nbuf, int Nn){
  const int node = (blockIdx.x * blockDim.x + threadIdx.x) >> 6;
  const int lane = threadIdx.x & 63;
  if(node >= Nn) return;
  const int half = lane >> 4;        // edge slot within group of 4
  const int li   = lane & 15;        // 16B slice of the 256B row
  const int s0 = rowptr[node];
  const int s1 = rowptr[node + 1];
  const float invd = (s1 > s0) ? (1.0f / (float)(s1 - s0)) : 0.0f;
  const uint cmax = (uint)(Nn - 1);
  float a[16];
  #pragma unroll
  for(int i = 0; i < 16; i++) a[i] = 0.f;

  #define DECODE_ACC(v)                                                        \
    {                                                                          \
      const uint uu[4] = {(v).x, (v).y, (v).z, (v).w};                         \
      _Pragma("unroll")                                                        \
      for(int m = 0; m < 4; m++){                                              \
        f32x2 lo = __builtin_amdgcn_cvt_pk_f32_fp8(uu[m], false);              \
        f32x2 hi = __builtin_amdgcn_cvt_pk_f32_fp8(uu[m], true);               \
        a[m*4+0] += lo.x; a[m*4+1] += lo.y;                                    \
        a[m*4+2] += hi.x; a[m*4+3] += hi.y;                                    \
      }                                                                        \
    }

  int e = s0;
  for(; e + 16 <= s1; e += 16){      // 4 uint4 loads in flight
    uint c[4];
    #pragma unroll
    for(int j = 0; j < 4; j++) c[j] = min((uint)colidx[e + j * 4 + half], cmax);
    uint4 v[4];
    #pragma unroll
    for(int j = 0; j < 4; j++) v[j] = *(const uint4*)(xq + (size_t)c[j] * 256 + li * 16);
    #pragma unroll
    for(int j = 0; j < 4; j++) DECODE_ACC(v[j]);
  }
  for(; e + 4 <= s1; e += 4){
    const uint c = min((uint)colidx[e + half], cmax);
    const uint4 v = *(const uint4*)(xq + (size_t)c * 256 + li * 16);
    DECODE_ACC(v);
  }
  if(half < s1 - e){                 // remainder < 4 edges
    const uint c = min((uint)colidx[e + half], cmax);
    const uint4 v = *(const uint4*)(xq + (size_t)c * 256 + li * 16);
    DECODE_ACC(v);
  }
  #undef DECODE_ACC

  #pragma unroll
  for(int i = 0; i < 16; i++){
    a[i] += __shfl_xor(a[i], 16);
    a[i] += __shfl_xor(a[i], 32);
  }
  if(lane < 16){
    uint4 o1, o2;
    o1.x = (uint)f2bf(a[ 0]*invd) | ((uint)f2bf(a[ 1]*invd) << 16);
    o1.y = (uint)f2bf(a[ 2]*invd) | ((uint)f2bf(a[ 3]*invd) << 16);
    o1.z = (uint)f2bf(a[ 4]*invd) | ((uint)f2bf(a[ 5]*invd) << 16);
    o1.w = (uint)f2bf(a[ 6]*invd) | ((uint)f2bf(a[ 7]*invd) << 16);
    o2.x = (uint)f2bf(a[ 8]*invd) | ((uint)f2bf(a[ 9]*invd) << 16);
    o2.y = (uint)f2bf(a[10]*invd) | ((uint)f2bf(a[11]*invd) << 16);
    o2.z = (uint)f2bf(a[12]*invd) | ((uint)f2bf(a[13]*invd) << 16);
    o2.w = (uint)f2bf(a[14]*invd) | ((uint)f2bf(a[15]*invd) << 16);
    ushort* p = nbuf + (size_t)node * DF + li * 16;
    *(uint4*)(p)     = o1;
    *(uint4*)(p + 8) = o2;
  }
}

// ------------------------- gather (mean-aggregate, bf16 rows) -------------------------
// Used for the layer-2 P-gather (dim 128). Same structure as round 7.

template<int DIMV>
__global__ __launch_bounds__(256)
void k_gather_b(const ushort* __restrict__ xb, const int* __restrict__ rowptr,
                const int* __restrict__ colidx, ushort* __restrict__ nbuf, int Nn){
  constexpr int LPR = DIMV / 8;
  constexpr int EPG = 64 / LPR;
  const int node = (blockIdx.x * blockDim.x + threadIdx.x) >> 6;
  const int lane = threadIdx.x & 63;
  if(node >= Nn) return;
  const int half = lane / LPR;
  const int li   = lane % LPR;
  const int s0 = rowptr[node];
  const int s1 = rowptr[node + 1];
  const float invd = (s1 > s0) ? (1.0f / (float)(s1 - s0)) : 0.0f;
  const uint cmax = (uint)(Nn - 1);
  float a[8] = {0.f,0.f,0.f,0.f,0.f,0.f,0.f,0.f};
  int e = s0;
  for(; e + 4 * EPG <= s1; e += 4 * EPG){
    uint c[4];
    #pragma unroll
    for(int j = 0; j < 4; j++) c[j] = min((uint)colidx[e + j * EPG + half], cmax);
    uint4 v[4];
    #pragma unroll
    for(int j = 0; j < 4; j++) v[j] = *(const uint4*)(xb + (size_t)c[j] * DIMV + li * 8);
    #pragma unroll
    for(int j = 0; j < 4; j++){
      a[0] += bflo(v[j].x); a[1] += bfhi(v[j].x);
      a[2] += bflo(v[j].y); a[3] += bfhi(v[j].y);
      a[4] += bflo(v[j].z); a[5] += bfhi(v[j].z);
      a[6] += bflo(v[j].w); a[7] += bfhi(v[j].w);
    }
  }
  for(; e + EPG <= s1; e += EPG){
    const uint c = min((uint)colidx[e + half], cmax);
    const uint4 v = *(const uint4*)(xb + (size_t)c * DIMV + li * 8);
    a[0] += bflo(v.x); a[1] += bfhi(v.x);
    a[2] += bflo(v.y); a[3] += bfhi(v.y);
    a[4] += bflo(v.z); a[5] += bfhi(v.z);
    a[6] += bflo(v.w); a[7] += bfhi(v.w);
  }
  if(half < s1 - e){
    const uint c = min((uint)colidx[e + half], cmax);
    const uint4 v = *(const uint4*)(xb + (size_t)c * DIMV + li * 8);
    a[0] += bflo(v.x); a[1] += bfhi(v.x);
    a[2] += bflo(v.y); a[3] += bfhi(v.y);
    a[4] += bflo(v.z); a[5] += bfhi(v.z);
    a[6] += bflo(v.w); a[7] += bfhi(v.w);
  }
  #pragma unroll
  for(int off = LPR; off < 64; off <<= 1)
    #pragma unroll
    for(int i = 0; i < 8; i++) a[i] += __shfl_xor(a[i], off);
  if(lane < LPR){
    uint4 o;
    o.x = (uint)f2bf(a[0]*invd) | ((uint)f2bf(a[1]*invd) << 16);
    o.y = (uint)f2bf(a[2]*invd) | ((uint)f2bf(a[3]*invd) << 16);
    o.z = (uint)f2bf(a[4]*invd) | ((uint)f2bf(a[5]*invd) << 16);
    o.w = (uint)f2bf(a[6]*invd) | ((uint)f2bf(a[7]*invd) << 16);
    *(uint4*)(nbuf + (size_t)node * DIMV + li * 8) = o;
  }
}

// ------------------------- MFMA MLP / projection -------------------------
// Per wave: 16 nodes. A-frag lane l holds A[l&15][s*32+(l>>4)*8+i]. TWOSRC: first
// KS/2 k-steps from A0, rest from A1 (concat). B from Wp (L2-hot). C layout:
// col=lane&15, row=(lane>>4)*4+reg. ADDG adds gathered bf16 term; NORM: bias+L2norm.

template<int DOUT, int KS, bool TWOSRC, bool ADDG, bool RELU, bool NORM, bool OUTBF16>
__launch_bounds__(256, 2)
__global__ void k_mlp(const ushort* __restrict__ A0, const ushort* __restrict__ A1,
                      const uint4* __restrict__ Wp, const float* __restrict__ bias,
                      const ushort* __restrict__ g,
                      ushort* __restrict__ outb, float* __restrict__ outf, int Nn)
{
  constexpr int NT   = DOUT / 16;
  constexpr int DIMA = TWOSRC ? KS * 16 : KS * 32;
  const int l     = threadIdx.x & 63;
  const int w     = threadIdx.x >> 6;
  const int nodeb = blockIdx.x * 64 + w * 16;
  const int grp   = l >> 4;
  const int li    = l & 15;

  const int rowL = min(nodeb + li, Nn - 1);
  uint4 a[KS];
  if(TWOSRC){
    const ushort* xr = A0 + (size_t)rowL * DIMA;
    const ushort* nr = A1 + (size_t)rowL * DIMA;
    #pragma unroll
    for(int s = 0; s < KS/2; s++) a[s]        = *(const uint4*)(xr + s * 32 + grp * 8);
    #pragma unroll
    for(int s = 0; s < KS/2; s++) a[s + KS/2] = *(const uint4*)(nr + s * 32 + grp * 8);
  } else {
    const ushort* xr = A0 + (size_t)rowL * DIMA;
    #pragma unroll
    for(int s = 0; s < KS; s++) a[s] = *(const uint4*)(xr + s * 32 + grp * 8);
  }

  f32x4 acc[NT];
  #pragma unroll
  for(int n = 0; n < NT; n++){
    f32x4 c = {0.f, 0.f, 0.f, 0.f};
    #pragma unroll
    for(int s = 0; s < KS; s++){
      const uint4 b = Wp[(size_t)(n * KS + s) * 64 + l];
      c = __builtin_amdgcn_mfma_f32_16x16x32_bf16(
            __builtin_bit_cast(bf16x8, a[s]),
            __builtin_bit_cast(bf16x8, b), c, 0, 0, 0);
    }
    acc[n] = c;
  }

  if(NORM){
    #pragma unroll
    for(int n = 0; n < NT; n++){
      const float bv = bias[n * 16 + li];
      acc[n][0] += bv; acc[n][1] += bv; acc[n][2] += bv; acc[n][3] += bv;
    }
  }

  if(ADDG){
    #pragma unroll
    for(int r = 0; r < 4; r++){
      const int rowg = min(nodeb + grp * 4 + r, Nn - 1);
      #pragma unroll
      for(int n = 0; n < NT; n++)
        acc[n][r] += bfs(g[(size_t)rowg * DOUT + n * 16 + li]);
    }
  }

  float rn[4] = {1.f, 1.f, 1.f, 1.f};
  if(NORM){
    #pragma unroll
    for(int r = 0; r < 4; r++){
      float ss = 0.f;
      #pragma unroll
      for(int n = 0; n < NT; n++) ss = fmaf(acc[n][r], acc[n][r], ss);
      ss += __shfl_xor(ss, 1);
      ss += __shfl_xor(ss, 2);
      ss += __shfl_xor(ss, 4);
      ss += __shfl_xor(ss, 8);
      rn[r] = 1.0f / fmaxf(sqrtf(ss), 1e-12f);
    }
  }

  #pragma unroll
  for(int r = 0; r < 4; r++){
    const int node = nodeb + grp * 4 + r;
    if(node < Nn){
      #pragma unroll
      for(int n = 0; n < NT; n++){
        float y = acc[n][r];
        if(NORM) y *= rn[r];
        if(RELU) y = fmaxf(y, 0.0f);
        const size_t idx = (size_t)node * DOUT + n * 16 + li;
        if(OUTBF16) outb[idx] = f2bf(y);
        else        outf[idx] = y;
      }
    }
  }
}

// ------------------------- host launch -------------------------

extern "C" void kernel_launch(void* const* d_in, const int* in_sizes, int n_in,
                              void* d_out, int out_size, void* d_ws, size_t ws_size,
                              hipStream_t stream) {
  const float* x    = (const float*)d_in[0];
  const int*   esrc = (const int*)  d_in[1];
  const int*   edst = (const int*)  d_in[2];
  // d_in[3] edge_val unused — it equals 1/deg(src), recomputed from CSR
  const float* W1   = (const float*)d_in[4];
  const float* b1   = (const float*)d_in[5];
  const float* W2   = (const float*)d_in[6];
  const float* b2   = (const float*)d_in[7];
  float* out = (float*)d_out;

  const int N = N_NODES, E = N_EDGES;

  char* ws = (char*)d_ws;
  size_t off = 0;
  auto alloc = [&](size_t bytes) -> void* {
    void* p = ws + off;
    off += (bytes + 255) & ~(size_t)255;
    return p;
  };
  int*    deg      = (int*)   alloc((size_t)N * 4);
  int*    rowptr   = (int*)   alloc((size_t)(N + 1) * 4);
  int*    cursor   = (int*)   alloc((size_t)N * 4);
  int*    partials = (int*)   alloc(512);
  int*    colidx   = (int*)   alloc((size_t)E * 4);
  ushort* xbuf     = (ushort*)alloc((size_t)N * DF * 2);   // bf16 mirror of x
  uchar*  xq       = (uchar*) alloc((size_t)N * DF);       // fp8 e4m3 mirror of x
  ushort* hbuf     = (ushort*)alloc((size_t)N * DF * 2);   // bf16 h (layer-1 out)
  ushort* nbuf     = (ushort*)alloc((size_t)N * DF * 2);   // layer1 neigh; reused as Pb|gb
  uint4*  Wp1      = (uint4*) alloc((size_t)16 * 16 * 64 * 16);  // W1: NT=16, KS=16
  uint4*  Wp2a     = (uint4*) alloc((size_t) 8 *  8 * 64 * 16);  // W2 rows 0..255
  uint4*  Wp2b     = (uint4*) alloc((size_t) 8 *  8 * 64 * 16);  // W2 rows 256..511
  if(off > ws_size) return;

  ushort* Pb = nbuf;                       // [N,128] bf16 projected features
  ushort* gb = nbuf + (size_t)N * 128;     // [N,128] bf16 gathered projection

  const int NBLK_SCAN = (N + 1023) / 1024;   // 98
  const int n8 = N * DF / 8;

  // bf16 + fp8 mirrors of x, zero deg/cursor in one pass
  k_cvt<<<(n8 + 255) / 256, 256, 0, stream>>>((const float4*)x, (uint4*)xbuf,
                                              (uint2*)xq, n8, deg, cursor, N);
  k_packw<256><<<(16 * 16 * 64 + 255) / 256, 256, 0, stream>>>(W1,  Wp1, 16, 0);
  k_packw<128><<<( 8 *  8 * 64 + 255) / 256, 256, 0, stream>>>(W2, Wp2a,  8, 0);
  k_packw<128><<<( 8 *  8 * 64 + 255) / 256, 256, 0, stream>>>(W2, Wp2b,  8, 256);

  k_hist <<<(E + 255) / 256, 256, 0, stream>>>(esrc, deg, E);
  k_scan1<<<NBLK_SCAN,       256, 0, stream>>>(deg, rowptr, partials, N);
  k_scan2<<<1,               128, 0, stream>>>(partials, NBLK_SCAN, rowptr, N, E);
  k_scan3<<<(N + 255) / 256, 256, 0, stream>>>(rowptr, partials, N);
  k_fill <<<(E + 255) / 256, 256, 0, stream>>>(esrc, edst, rowptr, cursor, colidx, E);

  const int GRID_MLP = (N + 63) / 64;   // 1563, tail-guarded

  // ---- layer 1: h = relu(normalize([x | mean_fp8(x)] @ W1 + b1))
  k_gather_q<<<N / 4, 256, 0, stream>>>(xq, rowptr, colidx, nbuf, N);
  k_mlp<256, 16, true, false, true, true, true>
      <<<GRID_MLP, 256, 0, stream>>>(xbuf, nbuf, Wp1, b1, nullptr, hbuf, nullptr, N);

  // ---- layer 2 (project-then-aggregate):
  //   P = h @ W2_bot ; out = normalize(h @ W2_top + mean(P) + b2)
  k_mlp<128, 8, false, false, false, false, true>
      <<<GRID_MLP, 256, 0, stream>>>(hbuf, nullptr, Wp2b, nullptr, nullptr, Pb, nullptr, N);
  k_gather_b<128><<<N / 4, 256, 0, stream>>>(Pb, rowptr, colidx, gb, N);
  k_mlp<128, 8, false, true, false, true, false>
      <<<GRID_MLP, 256, 0, stream>>>(hbuf, nullptr, Wp2a, b2, gb, nullptr, out, N);
}